// Round 5
// baseline (1098.616 us; speedup 1.0000x reference)
//
#include <hip/hip_runtime.h>
#include <math.h>

// GIN on MI355X. N=100000, E=1600000, H=F=64, C=10, diameter=6 (fixed).
// R5: (a) revert count/scatter to R3 one-edge-per-thread (R4's EPT=8 cut
//     occupancy 74->22% and regressed; scatter is random-write-BW bound);
//     (b) gin_step gather remapped: lane = 16*(edge subgroup) + feature-quad,
//     each lane loads float4 -> one VMEM instr covers 4 edge rows (4x MLP,
//     4x fewer instrs), with index prefetch; groups combined via 2 shfl_xor.
// gemm8 (no-spill, R3-verified) unchanged.

#define NPW 8   // nodes per wave; block = 4 waves = 32 nodes

// ---------- small utility kernels ----------
__global__ void zero_i32(int* __restrict__ p, int n) {
    int i = blockIdx.x * blockDim.x + threadIdx.x;
    if (i < n) p[i] = 0;
}

__global__ void count_deg(const int* __restrict__ dst, int E, int* __restrict__ deg) {
    int i = blockIdx.x * blockDim.x + threadIdx.x;
    if (i < E) atomicAdd(&deg[dst[i]], 1);
}

// inclusive scan within 256-element chunks
__global__ void scan1(const int* __restrict__ deg, int n,
                      int* __restrict__ incl, int* __restrict__ chunkSum) {
    __shared__ int s[256];
    int c = blockIdx.x;
    int i = c * 256 + threadIdx.x;
    int v = (i < n) ? deg[i] : 0;
    s[threadIdx.x] = v;
    __syncthreads();
    for (int off = 1; off < 256; off <<= 1) {
        int t = (threadIdx.x >= (unsigned)off) ? s[threadIdx.x - off] : 0;
        __syncthreads();
        s[threadIdx.x] += t;
        __syncthreads();
    }
    if (i < n) incl[i] = s[threadIdx.x];
    if (threadIdx.x == 255) chunkSum[c] = s[255];
}

// exclusive scan of chunk sums (nchunks <= 1024), in place
__global__ void scan2(int* __restrict__ chunkSum, int nchunks) {
    __shared__ int s[1024];
    int v = (threadIdx.x < (unsigned)nchunks) ? chunkSum[threadIdx.x] : 0;
    s[threadIdx.x] = v;
    __syncthreads();
    for (int off = 1; off < 1024; off <<= 1) {
        int t = (threadIdx.x >= (unsigned)off) ? s[threadIdx.x - off] : 0;
        __syncthreads();
        s[threadIdx.x] += t;
        __syncthreads();
    }
    if (threadIdx.x < (unsigned)nchunks) chunkSum[threadIdx.x] = s[threadIdx.x] - v;
}

// incl (in-place) -> exclusive rowstart; also init cursor
__global__ void scan3(int* __restrict__ incl_to_rowstart, const int* __restrict__ deg,
                      const int* __restrict__ chunkOff, int n, int* __restrict__ cursor) {
    int i = blockIdx.x * blockDim.x + threadIdx.x;
    if (i < n) {
        int rs = incl_to_rowstart[i] - deg[i] + chunkOff[i >> 8];
        incl_to_rowstart[i] = rs;
        cursor[i] = rs;
    }
}

__global__ void scatter_edges(const int* __restrict__ src, const int* __restrict__ dst, int E,
                              int* __restrict__ cursor, int* __restrict__ csr_src) {
    int i = blockIdx.x * blockDim.x + threadIdx.x;
    if (i < E) {
        int pos = atomicAdd(&cursor[dst[i]], 1);
        csr_src[pos] = src[i];
    }
}

// ---------- shared GEMM epilogue: acc[r] = bias + hs_row_r . W ----------
// W in LDS as Ws[k*64 + col] (2-way bank aliasing = free). Chunked:
// 8 k-values per chunk in wreg[8] only -> no spill (R3-verified).
__device__ __forceinline__ void gemm8(const float* __restrict__ Ws,
                                      const float (*hsw)[64],  // [NPW][64]
                                      float bias, int lane, float acc[NPW]) {
#pragma unroll
    for (int r = 0; r < NPW; r++) acc[r] = bias;
#pragma unroll 1
    for (int kc = 0; kc < 8; kc++) {
        float wreg[8];
#pragma unroll
        for (int j = 0; j < 8; j++) wreg[j] = Ws[(kc * 8 + j) * 64 + lane];
#pragma unroll
        for (int r = 0; r < NPW; r++) {
            float4 a = *(const float4*)&hsw[r][kc * 8];      // broadcast b128
            float4 c = *(const float4*)&hsw[r][kc * 8 + 4];  // broadcast b128
            acc[r] = fmaf(a.x, wreg[0], acc[r]);
            acc[r] = fmaf(a.y, wreg[1], acc[r]);
            acc[r] = fmaf(a.z, wreg[2], acc[r]);
            acc[r] = fmaf(a.w, wreg[3], acc[r]);
            acc[r] = fmaf(c.x, wreg[4], acc[r]);
            acc[r] = fmaf(c.y, wreg[5], acc[r]);
            acc[r] = fmaf(c.z, wreg[6], acc[r]);
            acc[r] = fmaf(c.w, wreg[7], acc[r]);
        }
    }
}

// ---------- encoder: h = x @ enc_w + enc_b ----------
__global__ __launch_bounds__(256, 4) void encode_k(const float* __restrict__ x,
                                                   const float* __restrict__ w,
                                                   const float* __restrict__ b,
                                                   float* __restrict__ h, int n) {
    __shared__ float Ws[64 * 64];
    __shared__ float hs[4][NPW][64];
    {
        const float4* w4 = (const float4*)w;
        float4* s4 = (float4*)Ws;
        for (int i = threadIdx.x; i < 1024; i += 256) s4[i] = w4[i];
    }
    int wv = threadIdx.x >> 6;
    int lane = threadIdx.x & 63;
    int base = (blockIdx.x * 4 + wv) * NPW;

#pragma unroll
    for (int r = 0; r < NPW; r++) {
        int node = base + r;
        if (node < n) hs[wv][r][lane] = x[(size_t)node * 64 + lane];
    }
    __syncthreads();

    float bias = b[lane];
    float acc[NPW];
    gemm8(Ws, hs[wv], bias, lane, acc);

#pragma unroll
    for (int r = 0; r < NPW; r++) {
        int node = base + r;
        if (node < n) h[(size_t)node * 64 + lane] = acc[r];
    }
}

// ---------- GIN step: agg = max over in-edges; h' = (h+agg)@W + b ----------
__global__ __launch_bounds__(256, 4) void gin_step_k(const float* __restrict__ hin,
                                                     float* __restrict__ hout,
                                                     const int* __restrict__ rowstart,
                                                     const int* __restrict__ rowend,
                                                     const int* __restrict__ csr_src,
                                                     const float* __restrict__ w,
                                                     const float* __restrict__ b, int n) {
    __shared__ float Ws[64 * 64];
    __shared__ float hs[4][NPW][64];
    {
        const float4* w4 = (const float4*)w;
        float4* s4 = (float4*)Ws;
        for (int i = threadIdx.x; i < 1024; i += 256) s4[i] = w4[i];
    }
    int wv = threadIdx.x >> 6;
    int lane = threadIdx.x & 63;
    int g = lane >> 4;    // edge subgroup 0..3 (each handles every 4th edge)
    int f = lane & 15;    // feature quad: features f*4 .. f*4+3
    int base = (blockIdx.x * 4 + wv) * NPW;

    // hoist self-row float4 loads (independent, go in flight early)
    float4 hv4[NPW];
#pragma unroll
    for (int r = 0; r < NPW; r++) {
        int node = base + r;
        if (node < n) hv4[r] = *(const float4*)&hin[(size_t)node * 64 + f * 4];
    }

    // phase 1: gather. One float4 per lane -> 4 edge rows per VMEM instr.
    for (int r = 0; r < NPW; r++) {
        int node = base + r;
        if (node >= n) break;
        int e0 = rowstart[node];
        int e1 = rowend[node];
        int deg = e1 - e0;
        float4 m4 = make_float4(-INFINITY, -INFINITY, -INFINITY, -INFINITY);
        if (deg >= 4) {
            int idx = csr_src[e0 + g];
            for (int e = e0; e + 4 <= e1; e += 4) {
                int idx_next = (e + 8 <= e1) ? csr_src[e + 4 + g] : 0;  // prefetch
                float4 v = *(const float4*)&hin[(size_t)idx * 64 + f * 4];
                m4.x = fmaxf(m4.x, v.x); m4.y = fmaxf(m4.y, v.y);
                m4.z = fmaxf(m4.z, v.z); m4.w = fmaxf(m4.w, v.w);
                idx = idx_next;
            }
        }
        int et = e0 + (deg & ~3);
        if (g < e1 - et) {  // tail 0..3 edges, one per group
            int ti = csr_src[et + g];
            float4 v = *(const float4*)&hin[(size_t)ti * 64 + f * 4];
            m4.x = fmaxf(m4.x, v.x); m4.y = fmaxf(m4.y, v.y);
            m4.z = fmaxf(m4.z, v.z); m4.w = fmaxf(m4.w, v.w);
        }
        // combine the 4 edge subgroups (lanes ^16, ^32)
        m4.x = fmaxf(m4.x, __shfl_xor(m4.x, 16));
        m4.y = fmaxf(m4.y, __shfl_xor(m4.y, 16));
        m4.z = fmaxf(m4.z, __shfl_xor(m4.z, 16));
        m4.w = fmaxf(m4.w, __shfl_xor(m4.w, 16));
        m4.x = fmaxf(m4.x, __shfl_xor(m4.x, 32));
        m4.y = fmaxf(m4.y, __shfl_xor(m4.y, 32));
        m4.z = fmaxf(m4.z, __shfl_xor(m4.z, 32));
        m4.w = fmaxf(m4.w, __shfl_xor(m4.w, 32));
        if (g == 0) {
            float4 t4;
            t4.x = hv4[r].x + ((deg > 0) ? m4.x : 0.0f);  // empty -> 0
            t4.y = hv4[r].y + ((deg > 0) ? m4.y : 0.0f);
            t4.z = hv4[r].z + ((deg > 0) ? m4.z : 0.0f);
            t4.w = hv4[r].w + ((deg > 0) ? m4.w : 0.0f);
            *(float4*)&hs[wv][r][f * 4] = t4;  // 16 lanes x b128 write
        }
    }
    __syncthreads();  // Ws ready; hs rows visible to whole wave

    float bias = b[lane];
    float acc[NPW];
    gemm8(Ws, hs[wv], bias, lane, acc);

#pragma unroll
    for (int r = 0; r < NPW; r++) {
        int node = base + r;
        if (node < n) hout[(size_t)node * 64 + lane] = acc[r];
    }
}

// ---------- decoder: log_softmax(h @ dec_w + dec_b), wave-per-node ----------
__global__ __launch_bounds__(256) void decode_k(const float* __restrict__ h,
                                                const float* __restrict__ w,
                                                const float* __restrict__ b,
                                                float* __restrict__ out, int n) {
    int wv = threadIdx.x >> 6;
    int lane = threadIdx.x & 63;
    int node = blockIdx.x * 4 + wv;
    if (node >= n) return;
    float hv = h[(size_t)node * 64 + lane];
    float l[10];
#pragma unroll
    for (int c = 0; c < 10; c++) l[c] = hv * w[lane * 10 + c];
#pragma unroll
    for (int off = 32; off >= 1; off >>= 1) {
#pragma unroll
        for (int c = 0; c < 10; c++) l[c] += __shfl_down(l[c], off);
    }
    if (lane == 0) {
        float mx = -INFINITY;
#pragma unroll
        for (int c = 0; c < 10; c++) { l[c] += b[c]; mx = fmaxf(mx, l[c]); }
        float sum = 0.0f;
#pragma unroll
        for (int c = 0; c < 10; c++) sum += expf(l[c] - mx);
        float lse = mx + logf(sum);
#pragma unroll
        for (int c = 0; c < 10; c++) out[(size_t)node * 10 + c] = l[c] - lse;
    }
}

extern "C" void kernel_launch(void* const* d_in, const int* in_sizes, int n_in,
                              void* d_out, int out_size, void* d_ws, size_t ws_size,
                              hipStream_t stream) {
    const float* x     = (const float*)d_in[0];
    const int*   ei    = (const int*)d_in[1];
    // d_in[2] = diameter (always 6; loop count must be static for graph capture)
    const float* enc_w = (const float*)d_in[3];
    const float* enc_b = (const float*)d_in[4];
    const float* proc_w = (const float*)d_in[5];
    const float* proc_b = (const float*)d_in[6];
    const float* dec_w = (const float*)d_in[7];
    const float* dec_b = (const float*)d_in[8];
    float* out = (float*)d_out;

    const int n = in_sizes[0] / 64;
    const int E = in_sizes[1] / 2;
    const int* src = ei;
    const int* dst = ei + E;

    // workspace carve (ws re-poisoned every call -> rebuild everything)
    char* p = (char*)d_ws;
    float* h_a = (float*)p;          p += (size_t)n * 64 * sizeof(float);
    float* h_b = (float*)p;          p += (size_t)n * 64 * sizeof(float);
    int* deg   = (int*)p;            p += (size_t)n * sizeof(int);
    int* rs    = (int*)p;            p += (size_t)n * sizeof(int);   // incl -> rowstart
    int* cur   = (int*)p;            p += (size_t)n * sizeof(int);   // cursor -> rowend
    int* chunk = (int*)p;            p += 1024 * sizeof(int);
    int* csr   = (int*)p;            p += (size_t)E * sizeof(int);

    const int nchunks = (n + 255) / 256;
    const int gN = (n + 255) / 256;
    const int gE = (E + 255) / 256;
    const int gTile = (n + 4 * NPW - 1) / (4 * NPW);
    const int gNode = (n + 3) / 4;

    // CSR build
    zero_i32<<<gN, 256, 0, stream>>>(deg, n);
    count_deg<<<gE, 256, 0, stream>>>(dst, E, deg);
    scan1<<<nchunks, 256, 0, stream>>>(deg, n, rs, chunk);
    scan2<<<1, 1024, 0, stream>>>(chunk, nchunks);
    scan3<<<gN, 256, 0, stream>>>(rs, deg, chunk, n, cur);
    scatter_edges<<<gE, 256, 0, stream>>>(src, dst, E, cur, csr);

    // encoder
    encode_k<<<gTile, 256, 0, stream>>>(x, enc_w, enc_b, h_a, n);

    // 6 GIN steps, ping-pong h_a <-> h_b
    float* hi = h_a;
    float* ho = h_b;
    for (int it = 0; it < 6; it++) {
        gin_step_k<<<gTile, 256, 0, stream>>>(hi, ho, rs, cur, csr, proc_w, proc_b, n);
        float* tmp = hi; hi = ho; ho = tmp;
    }

    // decoder (+ log_softmax)
    decode_k<<<gNode, 256, 0, stream>>>(hi, dec_w, dec_b, out, n);
}

// Round 6
// 1037.344 us; speedup vs baseline: 1.0591x; 1.0591x over previous
//
#include <hip/hip_runtime.h>
#include <math.h>

// GIN on MI355X. N=100000, E=1600000, H=F=64, C=10, diameter=6 (fixed).
// R6: activations stored as bf16 between kernels (gather rows 128B not 256B,
// working set 12.8MB -> better per-XCD L2 hit); ALL arithmetic fp32.
// Gather restored to R3/R4 shape: lane=feature, x8 unrolled independent
// row loads (8 MLP chains/wave — R5's 1-chain float4 remap regressed).
// CSR build: R3 one-edge-per-thread form (R4's EPT batching regressed).
// gemm8 (no-spill, R3-verified) unchanged.

#define NPW 8   // nodes per wave; block = 4 waves = 32 nodes

typedef unsigned short ushort_t;

__device__ __forceinline__ float b2f(ushort_t u) {
    union { unsigned u; float f; } v;
    v.u = ((unsigned)u) << 16;
    return v.f;
}
__device__ __forceinline__ ushort_t f2b(float x) {  // RNE bf16
    union { float f; unsigned u; } v;
    v.f = x;
    unsigned r = v.u + 0x7FFF + ((v.u >> 16) & 1);
    return (ushort_t)(r >> 16);
}

// ---------- small utility kernels ----------
__global__ void zero_i32(int* __restrict__ p, int n) {
    int i = blockIdx.x * blockDim.x + threadIdx.x;
    if (i < n) p[i] = 0;
}

__global__ void count_deg(const int* __restrict__ dst, int E, int* __restrict__ deg) {
    int i = blockIdx.x * blockDim.x + threadIdx.x;
    if (i < E) atomicAdd(&deg[dst[i]], 1);
}

// inclusive scan within 256-element chunks
__global__ void scan1(const int* __restrict__ deg, int n,
                      int* __restrict__ incl, int* __restrict__ chunkSum) {
    __shared__ int s[256];
    int c = blockIdx.x;
    int i = c * 256 + threadIdx.x;
    int v = (i < n) ? deg[i] : 0;
    s[threadIdx.x] = v;
    __syncthreads();
    for (int off = 1; off < 256; off <<= 1) {
        int t = (threadIdx.x >= (unsigned)off) ? s[threadIdx.x - off] : 0;
        __syncthreads();
        s[threadIdx.x] += t;
        __syncthreads();
    }
    if (i < n) incl[i] = s[threadIdx.x];
    if (threadIdx.x == 255) chunkSum[c] = s[255];
}

// exclusive scan of chunk sums (nchunks <= 1024), in place
__global__ void scan2(int* __restrict__ chunkSum, int nchunks) {
    __shared__ int s[1024];
    int v = (threadIdx.x < (unsigned)nchunks) ? chunkSum[threadIdx.x] : 0;
    s[threadIdx.x] = v;
    __syncthreads();
    for (int off = 1; off < 1024; off <<= 1) {
        int t = (threadIdx.x >= (unsigned)off) ? s[threadIdx.x - off] : 0;
        __syncthreads();
        s[threadIdx.x] += t;
        __syncthreads();
    }
    if (threadIdx.x < (unsigned)nchunks) chunkSum[threadIdx.x] = s[threadIdx.x] - v;
}

// incl (in-place) -> exclusive rowstart; also init cursor
__global__ void scan3(int* __restrict__ incl_to_rowstart, const int* __restrict__ deg,
                      const int* __restrict__ chunkOff, int n, int* __restrict__ cursor) {
    int i = blockIdx.x * blockDim.x + threadIdx.x;
    if (i < n) {
        int rs = incl_to_rowstart[i] - deg[i] + chunkOff[i >> 8];
        incl_to_rowstart[i] = rs;
        cursor[i] = rs;
    }
}

__global__ void scatter_edges(const int* __restrict__ src, const int* __restrict__ dst, int E,
                              int* __restrict__ cursor, int* __restrict__ csr_src) {
    int i = blockIdx.x * blockDim.x + threadIdx.x;
    if (i < E) {
        int pos = atomicAdd(&cursor[dst[i]], 1);
        csr_src[pos] = src[i];
    }
}

// ---------- shared GEMM epilogue: acc[r] = bias + hs_row_r . W ----------
// W in LDS as Ws[k*64 + col] (2-way bank aliasing = free). Chunked:
// 8 k-values per chunk in wreg[8] only -> no spill (R3-verified).
__device__ __forceinline__ void gemm8(const float* __restrict__ Ws,
                                      const float (*hsw)[64],  // [NPW][64]
                                      float bias, int lane, float acc[NPW]) {
#pragma unroll
    for (int r = 0; r < NPW; r++) acc[r] = bias;
#pragma unroll 1
    for (int kc = 0; kc < 8; kc++) {
        float wreg[8];
#pragma unroll
        for (int j = 0; j < 8; j++) wreg[j] = Ws[(kc * 8 + j) * 64 + lane];
#pragma unroll
        for (int r = 0; r < NPW; r++) {
            float4 a = *(const float4*)&hsw[r][kc * 8];      // broadcast b128
            float4 c = *(const float4*)&hsw[r][kc * 8 + 4];  // broadcast b128
            acc[r] = fmaf(a.x, wreg[0], acc[r]);
            acc[r] = fmaf(a.y, wreg[1], acc[r]);
            acc[r] = fmaf(a.z, wreg[2], acc[r]);
            acc[r] = fmaf(a.w, wreg[3], acc[r]);
            acc[r] = fmaf(c.x, wreg[4], acc[r]);
            acc[r] = fmaf(c.y, wreg[5], acc[r]);
            acc[r] = fmaf(c.z, wreg[6], acc[r]);
            acc[r] = fmaf(c.w, wreg[7], acc[r]);
        }
    }
}

// ---------- encoder: h = x @ enc_w + enc_b (fp32 in, bf16 out) ----------
__global__ __launch_bounds__(256, 4) void encode_k(const float* __restrict__ x,
                                                   const float* __restrict__ w,
                                                   const float* __restrict__ b,
                                                   ushort_t* __restrict__ hb, int n) {
    __shared__ float Ws[64 * 64];
    __shared__ float hs[4][NPW][64];
    {
        const float4* w4 = (const float4*)w;
        float4* s4 = (float4*)Ws;
        for (int i = threadIdx.x; i < 1024; i += 256) s4[i] = w4[i];
    }
    int wv = threadIdx.x >> 6;
    int lane = threadIdx.x & 63;
    int base = (blockIdx.x * 4 + wv) * NPW;

#pragma unroll
    for (int r = 0; r < NPW; r++) {
        int node = base + r;
        if (node < n) hs[wv][r][lane] = x[(size_t)node * 64 + lane];
    }
    __syncthreads();

    float bias = b[lane];
    float acc[NPW];
    gemm8(Ws, hs[wv], bias, lane, acc);

#pragma unroll
    for (int r = 0; r < NPW; r++) {
        int node = base + r;
        if (node < n) hb[(size_t)node * 64 + lane] = f2b(acc[r]);
    }
}

// ---------- GIN step: agg = max over in-edges; h' = (h+agg)@W + b ----------
// hin/hout are bf16; all arithmetic fp32.
__global__ __launch_bounds__(256, 4) void gin_step_k(const ushort_t* __restrict__ hin,
                                                     ushort_t* __restrict__ hout,
                                                     const int* __restrict__ rowstart,
                                                     const int* __restrict__ rowend,
                                                     const int* __restrict__ csr_src,
                                                     const float* __restrict__ w,
                                                     const float* __restrict__ b, int n) {
    __shared__ float Ws[64 * 64];
    __shared__ float hs[4][NPW][64];
    {
        const float4* w4 = (const float4*)w;
        float4* s4 = (float4*)Ws;
        for (int i = threadIdx.x; i < 1024; i += 256) s4[i] = w4[i];
    }
    int wv = threadIdx.x >> 6;
    int lane = threadIdx.x & 63;
    int base = (blockIdx.x * 4 + wv) * NPW;

    // hoist self-rows: 8 independent loads in flight before the edge loops
    float hv[NPW];
#pragma unroll
    for (int r = 0; r < NPW; r++) {
        int node = base + r;
        hv[r] = (node < n) ? b2f(hin[(size_t)node * 64 + lane]) : 0.0f;
    }

    // phase 1: gather (max over in-edges), x8 unrolled -> 8 row loads in flight
    for (int r = 0; r < NPW; r++) {
        int node = base + r;
        if (node >= n) break;
        int e0 = rowstart[node];
        int e1 = rowend[node];
        float m = -INFINITY;
        int e = e0;
        for (; e + 8 <= e1; e += 8) {
            int s[8];
#pragma unroll
            for (int j = 0; j < 8; j++) s[j] = csr_src[e + j];
            float a[8];
#pragma unroll
            for (int j = 0; j < 8; j++) a[j] = b2f(hin[(size_t)s[j] * 64 + lane]);
            float m01 = fmaxf(a[0], a[1]), m23 = fmaxf(a[2], a[3]);
            float m45 = fmaxf(a[4], a[5]), m67 = fmaxf(a[6], a[7]);
            m = fmaxf(m, fmaxf(fmaxf(m01, m23), fmaxf(m45, m67)));
        }
        for (; e < e1; e++) m = fmaxf(m, b2f(hin[(size_t)csr_src[e] * 64 + lane]));
        float agg = (e0 < e1) ? m : 0.0f;  // empty segment -> 0 (isfinite fixup)
        hs[wv][r][lane] = hv[r] + agg;
    }
    __syncthreads();  // Ws ready (hs is wave-private, Ws is block-shared)

    float bias = b[lane];
    float acc[NPW];
    gemm8(Ws, hs[wv], bias, lane, acc);

#pragma unroll
    for (int r = 0; r < NPW; r++) {
        int node = base + r;
        if (node < n) hout[(size_t)node * 64 + lane] = f2b(acc[r]);
    }
}

// ---------- decoder: log_softmax(h @ dec_w + dec_b), wave-per-node ----------
__global__ __launch_bounds__(256) void decode_k(const ushort_t* __restrict__ h,
                                                const float* __restrict__ w,
                                                const float* __restrict__ b,
                                                float* __restrict__ out, int n) {
    int wv = threadIdx.x >> 6;
    int lane = threadIdx.x & 63;
    int node = blockIdx.x * 4 + wv;
    if (node >= n) return;
    float hv = b2f(h[(size_t)node * 64 + lane]);
    float l[10];
#pragma unroll
    for (int c = 0; c < 10; c++) l[c] = hv * w[lane * 10 + c];
#pragma unroll
    for (int off = 32; off >= 1; off >>= 1) {
#pragma unroll
        for (int c = 0; c < 10; c++) l[c] += __shfl_down(l[c], off);
    }
    if (lane == 0) {
        float mx = -INFINITY;
#pragma unroll
        for (int c = 0; c < 10; c++) { l[c] += b[c]; mx = fmaxf(mx, l[c]); }
        float sum = 0.0f;
#pragma unroll
        for (int c = 0; c < 10; c++) sum += expf(l[c] - mx);
        float lse = mx + logf(sum);
#pragma unroll
        for (int c = 0; c < 10; c++) out[(size_t)node * 10 + c] = l[c] - lse;
    }
}

extern "C" void kernel_launch(void* const* d_in, const int* in_sizes, int n_in,
                              void* d_out, int out_size, void* d_ws, size_t ws_size,
                              hipStream_t stream) {
    const float* x     = (const float*)d_in[0];
    const int*   ei    = (const int*)d_in[1];
    // d_in[2] = diameter (always 6; loop count must be static for graph capture)
    const float* enc_w = (const float*)d_in[3];
    const float* enc_b = (const float*)d_in[4];
    const float* proc_w = (const float*)d_in[5];
    const float* proc_b = (const float*)d_in[6];
    const float* dec_w = (const float*)d_in[7];
    const float* dec_b = (const float*)d_in[8];
    float* out = (float*)d_out;

    const int n = in_sizes[0] / 64;
    const int E = in_sizes[1] / 2;
    const int* src = ei;
    const int* dst = ei + E;

    // workspace carve (ws re-poisoned every call -> rebuild everything)
    char* p = (char*)d_ws;
    ushort_t* hb_a = (ushort_t*)p;   p += (size_t)n * 64 * sizeof(ushort_t);
    ushort_t* hb_b = (ushort_t*)p;   p += (size_t)n * 64 * sizeof(ushort_t);
    int* deg   = (int*)p;            p += (size_t)n * sizeof(int);
    int* rs    = (int*)p;            p += (size_t)n * sizeof(int);   // incl -> rowstart
    int* cur   = (int*)p;            p += (size_t)n * sizeof(int);   // cursor -> rowend
    int* chunk = (int*)p;            p += 1024 * sizeof(int);
    int* csr   = (int*)p;            p += (size_t)E * sizeof(int);

    const int nchunks = (n + 255) / 256;
    const int gN = (n + 255) / 256;
    const int gE = (E + 255) / 256;
    const int gTile = (n + 4 * NPW - 1) / (4 * NPW);
    const int gNode = (n + 3) / 4;

    // CSR build
    zero_i32<<<gN, 256, 0, stream>>>(deg, n);
    count_deg<<<gE, 256, 0, stream>>>(dst, E, deg);
    scan1<<<nchunks, 256, 0, stream>>>(deg, n, rs, chunk);
    scan2<<<1, 1024, 0, stream>>>(chunk, nchunks);
    scan3<<<gN, 256, 0, stream>>>(rs, deg, chunk, n, cur);
    scatter_edges<<<gE, 256, 0, stream>>>(src, dst, E, cur, csr);

    // encoder
    encode_k<<<gTile, 256, 0, stream>>>(x, enc_w, enc_b, hb_a, n);

    // 6 GIN steps, ping-pong hb_a <-> hb_b (ends in hb_a)
    ushort_t* hi = hb_a;
    ushort_t* ho = hb_b;
    for (int it = 0; it < 6; it++) {
        gin_step_k<<<gTile, 256, 0, stream>>>(hi, ho, rs, cur, csr, proc_w, proc_b, n);
        ushort_t* tmp = hi; hi = ho; ho = tmp;
    }

    // decoder (+ log_softmax)
    decode_k<<<gNode, 256, 0, stream>>>(hi, dec_w, dec_b, out, n);
}

// Round 7
// 885.448 us; speedup vs baseline: 1.2407x; 1.1715x over previous
//
#include <hip/hip_runtime.h>
#include <math.h>

// GIN on MI355X. N=100000, E=1600000, H=F=64, C=10, diameter=6 (fixed).
// R7: fp32 activations (bf16 was neutral/worse: gather is latency-ROUND
// bound, not byte bound). CSR rows padded to multiples of 8 with sentinel
// edges -> a node-row n filled with -INF; the serial scalar tail (avg ~3.5
// 1-load rounds/node, ~60% of gather latency rounds) is eliminated.
// Indices load as int4 pairs (8-aligned rows). gemm8 (no-spill) unchanged.

#define NPW 8   // nodes per wave; block = 4 waves = 32 nodes

// ---------- small utility kernels ----------
__global__ void zero_i32(int* __restrict__ p, int n) {
    int i = blockIdx.x * blockDim.x + threadIdx.x;
    if (i < n) p[i] = 0;
}

__global__ void fill_i32(int* __restrict__ p, int n, int val) {
    int i = blockIdx.x * blockDim.x + threadIdx.x;
    if (i < n) p[i] = val;
}

// sentinel row n of both h buffers = -INF (re-poisoned ws -> every call)
__global__ void fill_sentinel(float* __restrict__ ha, float* __restrict__ hb, int n) {
    int lane = threadIdx.x;
    if (lane < 64) {
        ha[(size_t)n * 64 + lane] = -INFINITY;
        hb[(size_t)n * 64 + lane] = -INFINITY;
    }
}

__global__ void count_deg(const int* __restrict__ dst, int E, int* __restrict__ deg) {
    int i = blockIdx.x * blockDim.x + threadIdx.x;
    if (i < E) atomicAdd(&deg[dst[i]], 1);
}

// inclusive scan of PADDED degrees within 256-element chunks
__global__ void scan1(const int* __restrict__ deg, int n,
                      int* __restrict__ incl, int* __restrict__ chunkSum) {
    __shared__ int s[256];
    int c = blockIdx.x;
    int i = c * 256 + threadIdx.x;
    int v = (i < n) ? ((deg[i] + 7) & ~7) : 0;   // padded degree
    s[threadIdx.x] = v;
    __syncthreads();
    for (int off = 1; off < 256; off <<= 1) {
        int t = (threadIdx.x >= (unsigned)off) ? s[threadIdx.x - off] : 0;
        __syncthreads();
        s[threadIdx.x] += t;
        __syncthreads();
    }
    if (i < n) incl[i] = s[threadIdx.x];
    if (threadIdx.x == 255) chunkSum[c] = s[255];
}

// exclusive scan of chunk sums (nchunks <= 1024), in place
__global__ void scan2(int* __restrict__ chunkSum, int nchunks) {
    __shared__ int s[1024];
    int v = (threadIdx.x < (unsigned)nchunks) ? chunkSum[threadIdx.x] : 0;
    s[threadIdx.x] = v;
    __syncthreads();
    for (int off = 1; off < 1024; off <<= 1) {
        int t = (threadIdx.x >= (unsigned)off) ? s[threadIdx.x - off] : 0;
        __syncthreads();
        s[threadIdx.x] += t;
        __syncthreads();
    }
    if (threadIdx.x < (unsigned)nchunks) chunkSum[threadIdx.x] = s[threadIdx.x] - v;
}

// incl (in-place, padded) -> exclusive padded rowstart; init cursor
__global__ void scan3(int* __restrict__ incl_to_rowstart, const int* __restrict__ deg,
                      const int* __restrict__ chunkOff, int n, int* __restrict__ cursor) {
    int i = blockIdx.x * blockDim.x + threadIdx.x;
    if (i < n) {
        int dpad = (deg[i] + 7) & ~7;
        int rs = incl_to_rowstart[i] - dpad + chunkOff[i >> 8];
        incl_to_rowstart[i] = rs;
        cursor[i] = rs;
    }
}

__global__ void scatter_edges(const int* __restrict__ src, const int* __restrict__ dst, int E,
                              int* __restrict__ cursor, int* __restrict__ csr_src) {
    int i = blockIdx.x * blockDim.x + threadIdx.x;
    if (i < E) {
        int pos = atomicAdd(&cursor[dst[i]], 1);
        csr_src[pos] = src[i];
    }
}

// ---------- shared GEMM epilogue: acc[r] = bias + hs_row_r . W ----------
// W in LDS as Ws[k*64 + col] (2-way bank aliasing = free). Chunked:
// 8 k-values per chunk in wreg[8] only -> no spill (R3-verified).
__device__ __forceinline__ void gemm8(const float* __restrict__ Ws,
                                      const float (*hsw)[64],  // [NPW][64]
                                      float bias, int lane, float acc[NPW]) {
#pragma unroll
    for (int r = 0; r < NPW; r++) acc[r] = bias;
#pragma unroll 1
    for (int kc = 0; kc < 8; kc++) {
        float wreg[8];
#pragma unroll
        for (int j = 0; j < 8; j++) wreg[j] = Ws[(kc * 8 + j) * 64 + lane];
#pragma unroll
        for (int r = 0; r < NPW; r++) {
            float4 a = *(const float4*)&hsw[r][kc * 8];      // broadcast b128
            float4 c = *(const float4*)&hsw[r][kc * 8 + 4];  // broadcast b128
            acc[r] = fmaf(a.x, wreg[0], acc[r]);
            acc[r] = fmaf(a.y, wreg[1], acc[r]);
            acc[r] = fmaf(a.z, wreg[2], acc[r]);
            acc[r] = fmaf(a.w, wreg[3], acc[r]);
            acc[r] = fmaf(c.x, wreg[4], acc[r]);
            acc[r] = fmaf(c.y, wreg[5], acc[r]);
            acc[r] = fmaf(c.z, wreg[6], acc[r]);
            acc[r] = fmaf(c.w, wreg[7], acc[r]);
        }
    }
}

// ---------- encoder: h = x @ enc_w + enc_b ----------
__global__ __launch_bounds__(256, 4) void encode_k(const float* __restrict__ x,
                                                   const float* __restrict__ w,
                                                   const float* __restrict__ b,
                                                   float* __restrict__ h, int n) {
    __shared__ float Ws[64 * 64];
    __shared__ float hs[4][NPW][64];
    {
        const float4* w4 = (const float4*)w;
        float4* s4 = (float4*)Ws;
        for (int i = threadIdx.x; i < 1024; i += 256) s4[i] = w4[i];
    }
    int wv = threadIdx.x >> 6;
    int lane = threadIdx.x & 63;
    int base = (blockIdx.x * 4 + wv) * NPW;

#pragma unroll
    for (int r = 0; r < NPW; r++) {
        int node = base + r;
        if (node < n) hs[wv][r][lane] = x[(size_t)node * 64 + lane];
    }
    __syncthreads();

    float bias = b[lane];
    float acc[NPW];
    gemm8(Ws, hs[wv], bias, lane, acc);

#pragma unroll
    for (int r = 0; r < NPW; r++) {
        int node = base + r;
        if (node < n) h[(size_t)node * 64 + lane] = acc[r];
    }
}

// ---------- GIN step: agg = max over in-edges; h' = (h+agg)@W + b ----------
// CSR rows are padded to x8 with sentinel index n (row n = -INF).
__global__ __launch_bounds__(256, 4) void gin_step_k(const float* __restrict__ hin,
                                                     float* __restrict__ hout,
                                                     const int* __restrict__ rowstart,
                                                     const int* __restrict__ degarr,
                                                     const int* __restrict__ csr_src,
                                                     const float* __restrict__ w,
                                                     const float* __restrict__ b, int n) {
    __shared__ float Ws[64 * 64];
    __shared__ float hs[4][NPW][64];
    {
        const float4* w4 = (const float4*)w;
        float4* s4 = (float4*)Ws;
        for (int i = threadIdx.x; i < 1024; i += 256) s4[i] = w4[i];
    }
    int wv = threadIdx.x >> 6;
    int lane = threadIdx.x & 63;
    int base = (blockIdx.x * 4 + wv) * NPW;

    // hoist self-rows: 8 independent loads in flight before the edge loops
    float hv[NPW];
#pragma unroll
    for (int r = 0; r < NPW; r++) {
        int node = base + r;
        hv[r] = (node < n) ? hin[(size_t)node * 64 + lane] : 0.0f;
    }

    // phase 1: gather. Rows padded to x8 -> no scalar tail; indices via int4.
    for (int r = 0; r < NPW; r++) {
        int node = base + r;
        if (node >= n) break;
        int e0 = rowstart[node];
        int d = degarr[node];
        int rounds = (d + 7) >> 3;
        float m = -INFINITY;
        const int4* ip = (const int4*)&csr_src[e0];  // e0 is 8-aligned
        for (int k = 0; k < rounds; k++) {
            int4 i0 = ip[2 * k];
            int4 i1 = ip[2 * k + 1];
            float a0 = hin[(size_t)i0.x * 64 + lane];
            float a1 = hin[(size_t)i0.y * 64 + lane];
            float a2 = hin[(size_t)i0.z * 64 + lane];
            float a3 = hin[(size_t)i0.w * 64 + lane];
            float a4 = hin[(size_t)i1.x * 64 + lane];
            float a5 = hin[(size_t)i1.y * 64 + lane];
            float a6 = hin[(size_t)i1.z * 64 + lane];
            float a7 = hin[(size_t)i1.w * 64 + lane];
            float m01 = fmaxf(a0, a1), m23 = fmaxf(a2, a3);
            float m45 = fmaxf(a4, a5), m67 = fmaxf(a6, a7);
            m = fmaxf(m, fmaxf(fmaxf(m01, m23), fmaxf(m45, m67)));
        }
        float agg = (d > 0) ? m : 0.0f;  // empty segment -> 0 (isfinite fixup)
        hs[wv][r][lane] = hv[r] + agg;
    }
    __syncthreads();  // Ws ready (hs is wave-private, Ws is block-shared)

    float bias = b[lane];
    float acc[NPW];
    gemm8(Ws, hs[wv], bias, lane, acc);

#pragma unroll
    for (int r = 0; r < NPW; r++) {
        int node = base + r;
        if (node < n) hout[(size_t)node * 64 + lane] = acc[r];
    }
}

// ---------- decoder: log_softmax(h @ dec_w + dec_b), wave-per-node ----------
__global__ __launch_bounds__(256) void decode_k(const float* __restrict__ h,
                                                const float* __restrict__ w,
                                                const float* __restrict__ b,
                                                float* __restrict__ out, int n) {
    int wv = threadIdx.x >> 6;
    int lane = threadIdx.x & 63;
    int node = blockIdx.x * 4 + wv;
    if (node >= n) return;
    float hv = h[(size_t)node * 64 + lane];
    float l[10];
#pragma unroll
    for (int c = 0; c < 10; c++) l[c] = hv * w[lane * 10 + c];
#pragma unroll
    for (int off = 32; off >= 1; off >>= 1) {
#pragma unroll
        for (int c = 0; c < 10; c++) l[c] += __shfl_down(l[c], off);
    }
    if (lane == 0) {
        float mx = -INFINITY;
#pragma unroll
        for (int c = 0; c < 10; c++) { l[c] += b[c]; mx = fmaxf(mx, l[c]); }
        float sum = 0.0f;
#pragma unroll
        for (int c = 0; c < 10; c++) sum += expf(l[c] - mx);
        float lse = mx + logf(sum);
#pragma unroll
        for (int c = 0; c < 10; c++) out[(size_t)node * 10 + c] = l[c] - lse;
    }
}

extern "C" void kernel_launch(void* const* d_in, const int* in_sizes, int n_in,
                              void* d_out, int out_size, void* d_ws, size_t ws_size,
                              hipStream_t stream) {
    const float* x     = (const float*)d_in[0];
    const int*   ei    = (const int*)d_in[1];
    // d_in[2] = diameter (always 6; loop count must be static for graph capture)
    const float* enc_w = (const float*)d_in[3];
    const float* enc_b = (const float*)d_in[4];
    const float* proc_w = (const float*)d_in[5];
    const float* proc_b = (const float*)d_in[6];
    const float* dec_w = (const float*)d_in[7];
    const float* dec_b = (const float*)d_in[8];
    float* out = (float*)d_out;

    const int n = in_sizes[0] / 64;
    const int E = in_sizes[1] / 2;
    const int* src = ei;
    const int* dst = ei + E;

    const int Epad = E + 7 * ((n + 7) & ~7);  // upper bound on padded edges

    // workspace carve (ws re-poisoned every call -> rebuild everything)
    // h buffers have n+1 rows; row n is the -INF sentinel row.
    char* p = (char*)d_ws;
    float* h_a = (float*)p;          p += (size_t)(n + 1) * 64 * sizeof(float);
    float* h_b = (float*)p;          p += (size_t)(n + 1) * 64 * sizeof(float);
    int* deg   = (int*)p;            p += (size_t)n * sizeof(int);
    int* rs    = (int*)p;            p += (size_t)n * sizeof(int);   // padded rowstart
    int* cur   = (int*)p;            p += (size_t)n * sizeof(int);   // scatter cursor
    int* chunk = (int*)p;            p += 1024 * sizeof(int);
    int* csr   = (int*)p;            p += (size_t)Epad * sizeof(int);

    const int nchunks = (n + 255) / 256;
    const int gN = (n + 255) / 256;
    const int gE = (E + 255) / 256;
    const int gEpad = (Epad + 255) / 256;
    const int gTile = (n + 4 * NPW - 1) / (4 * NPW);
    const int gNode = (n + 3) / 4;

    // CSR build (padded): prefill csr with sentinel n, then scatter real edges
    zero_i32<<<gN, 256, 0, stream>>>(deg, n);
    fill_i32<<<gEpad, 256, 0, stream>>>(csr, Epad, n);
    fill_sentinel<<<1, 64, 0, stream>>>(h_a, h_b, n);
    count_deg<<<gE, 256, 0, stream>>>(dst, E, deg);
    scan1<<<nchunks, 256, 0, stream>>>(deg, n, rs, chunk);
    scan2<<<1, 1024, 0, stream>>>(chunk, nchunks);
    scan3<<<gN, 256, 0, stream>>>(rs, deg, chunk, n, cur);
    scatter_edges<<<gE, 256, 0, stream>>>(src, dst, E, cur, csr);

    // encoder
    encode_k<<<gTile, 256, 0, stream>>>(x, enc_w, enc_b, h_a, n);

    // 6 GIN steps, ping-pong h_a <-> h_b (ends in h_a)
    float* hi = h_a;
    float* ho = h_b;
    for (int it = 0; it < 6; it++) {
        gin_step_k<<<gTile, 256, 0, stream>>>(hi, ho, rs, deg, csr, proc_w, proc_b, n);
        float* tmp = hi; hi = ho; ho = tmp;
    }

    // decoder (+ log_softmax)
    decode_k<<<gNode, 256, 0, stream>>>(hi, dec_w, dec_b, out, n);
}